// Round 1
// baseline (570.414 us; speedup 1.0000x reference)
//
#include <hip/hip_runtime.h>

#define Bb 8
#define Tt 4096
#define Hh 1024
#define Mm 2048
#define Kk 32
#define Rr 1024

// ---------------------------------------------------------------------------
// Stage 1: weighted[q,d] = sum_k scores[q,k] * values[q,k,d]
// One block per mention q, 256 threads, float4 (each thread owns 4 dims).
// Memory-bound: 256 MB read.
// ---------------------------------------------------------------------------
__global__ __launch_bounds__(256) void k_weighted(
    const float* __restrict__ scores,   // [M,K]
    const float* __restrict__ values,   // [M,K,R]
    float* __restrict__ weighted) {     // [M,R]
  int q = blockIdx.x;
  int t = threadIdx.x;
  __shared__ float s[Kk];
  if (t < Kk) s[t] = scores[q * Kk + t];
  __syncthreads();
  const float4* vv = (const float4*)(values + (size_t)q * Kk * Rr);
  float4 acc = make_float4(0.f, 0.f, 0.f, 0.f);
#pragma unroll 8
  for (int k = 0; k < Kk; ++k) {
    float4 v = vv[k * (Rr / 4) + t];
    float sk = s[k];
    acc.x += sk * v.x; acc.y += sk * v.y; acc.z += sk * v.z; acc.w += sk * v.w;
  }
  ((float4*)(weighted + (size_t)q * Rr))[t] = acc;
}

// ---------------------------------------------------------------------------
// Stage 2: proj = (weighted @ W + b) * mask   [M,H]
// fp32 vector GEMM (no fp32 MFMA on CDNA4). 64x64 tile, BK=16, 256 threads,
// 4x4 per-thread microtile. Grid 16x32 = 512 blocks (2 per CU).
// ---------------------------------------------------------------------------
__global__ __launch_bounds__(256) void k_gemm(
    const float* __restrict__ A,       // [M,R] weighted
    const float* __restrict__ Wm,      // [R,H]
    const float* __restrict__ bias,    // [H]
    const int* __restrict__ mask,      // [M]
    float* __restrict__ C) {           // [M,H]
  __shared__ float As[16][64];  // transposed A tile: As[k][m]
  __shared__ float Bs[16][64];  // Bs[k][n]
  int bn = blockIdx.x * 64;
  int bm = blockIdx.y * 64;
  int tid = threadIdx.x;
  int tx = tid & 15;        // n quadrant
  int ty = tid >> 4;        // m quadrant
  int arow = tid >> 2, ac4 = tid & 3;   // A-tile load mapping
  int brow = tid >> 4, bc4 = tid & 15;  // B-tile load mapping

  float acc[4][4];
#pragma unroll
  for (int i = 0; i < 4; ++i)
#pragma unroll
    for (int j = 0; j < 4; ++j) acc[i][j] = 0.f;

  for (int k0 = 0; k0 < Rr; k0 += 16) {
    float4 a = *(const float4*)(A + (size_t)(bm + arow) * Rr + k0 + ac4 * 4);
    float4 bv = *(const float4*)(Wm + (size_t)(k0 + brow) * Hh + bn + bc4 * 4);
    __syncthreads();  // previous iteration's reads done before overwrite
    As[ac4 * 4 + 0][arow] = a.x;
    As[ac4 * 4 + 1][arow] = a.y;
    As[ac4 * 4 + 2][arow] = a.z;
    As[ac4 * 4 + 3][arow] = a.w;
    *(float4*)(&Bs[brow][bc4 * 4]) = bv;
    __syncthreads();
#pragma unroll
    for (int kk = 0; kk < 16; ++kk) {
      float4 av = *(const float4*)(&As[kk][ty * 4]);
      float4 bw = *(const float4*)(&Bs[kk][tx * 4]);
      acc[0][0] += av.x * bw.x; acc[0][1] += av.x * bw.y; acc[0][2] += av.x * bw.z; acc[0][3] += av.x * bw.w;
      acc[1][0] += av.y * bw.x; acc[1][1] += av.y * bw.y; acc[1][2] += av.y * bw.z; acc[1][3] += av.y * bw.w;
      acc[2][0] += av.z * bw.x; acc[2][1] += av.z * bw.y; acc[2][2] += av.z * bw.z; acc[2][3] += av.z * bw.w;
      acc[3][0] += av.w * bw.x; acc[3][1] += av.w * bw.y; acc[3][2] += av.w * bw.z; acc[3][3] += av.w * bw.w;
    }
  }

  float4 bias4 = *(const float4*)(bias + bn + tx * 4);
#pragma unroll
  for (int i = 0; i < 4; ++i) {
    int row = bm + ty * 4 + i;
    float mk = (float)mask[row];
    float4 o;
    o.x = (acc[i][0] + bias4.x) * mk;
    o.y = (acc[i][1] + bias4.y) * mk;
    o.z = (acc[i][2] + bias4.z) * mk;
    o.w = (acc[i][3] + bias4.w) * mk;
    *(float4*)(C + (size_t)row * Hh + bn + tx * 4) = o;
  }
}

// ---------------------------------------------------------------------------
// Stage 3: per-row linked list of mentions (handles duplicate (b,s) pairs).
// ---------------------------------------------------------------------------
__global__ void k_init_head(int* __restrict__ head) {
  int i = blockIdx.x * 256 + threadIdx.x;
  if (i < Bb * Tt) head[i] = -1;
}

__global__ void k_link(const int* __restrict__ bpos, const int* __restrict__ spos,
                       const int* __restrict__ mask, int* __restrict__ head,
                       int* __restrict__ nxt) {
  int m = blockIdx.x * 256 + threadIdx.x;
  if (m < Mm && mask[m] != 0) {
    int row = bpos[m] * Tt + spos[m];
    nxt[m] = atomicExch(&head[row], m);  // device-scope, duplicates chain
  }
}

// ---------------------------------------------------------------------------
// Stage 4: fused scatter-add + LayerNorm. One block per (b,t) row.
// Two-pass mean/var (matches mean((x-mean)^2) numerics).
// ---------------------------------------------------------------------------
__global__ __launch_bounds__(256) void k_ln(
    const float* __restrict__ x,       // [B,T,H] encoded_input
    const float* __restrict__ proj,    // [M,H]
    const int* __restrict__ head, const int* __restrict__ nxt,
    const float* __restrict__ scale, const float* __restrict__ bias,
    float* __restrict__ out) {
  int row = blockIdx.x;
  int t = threadIdx.x;
  float4 v = ((const float4*)(x + (size_t)row * Hh))[t];
  for (int m = head[row]; m >= 0; m = nxt[m]) {
    float4 p = ((const float4*)(proj + (size_t)m * Hh))[t];
    v.x += p.x; v.y += p.y; v.z += p.z; v.w += p.w;
  }
  __shared__ float sbuf[4];
  int lane = t & 63, wave = t >> 6;

  float sum = v.x + v.y + v.z + v.w;
#pragma unroll
  for (int off = 32; off; off >>= 1) sum += __shfl_down(sum, off);
  if (lane == 0) sbuf[wave] = sum;
  __syncthreads();
  float mean = (sbuf[0] + sbuf[1] + sbuf[2] + sbuf[3]) * (1.0f / Hh);
  __syncthreads();

  float cx = v.x - mean, cy = v.y - mean, cz = v.z - mean, cw = v.w - mean;
  float ssq = cx * cx + cy * cy + cz * cz + cw * cw;
#pragma unroll
  for (int off = 32; off; off >>= 1) ssq += __shfl_down(ssq, off);
  if (lane == 0) sbuf[wave] = ssq;
  __syncthreads();
  float var = (sbuf[0] + sbuf[1] + sbuf[2] + sbuf[3]) * (1.0f / Hh);
  float inv = 1.0f / sqrtf(var + 1e-12f);

  float4 sc = ((const float4*)scale)[t];
  float4 bi = ((const float4*)bias)[t];
  float4 o;
  o.x = cx * inv * sc.x + bi.x;
  o.y = cy * inv * sc.y + bi.y;
  o.z = cz * inv * sc.z + bi.z;
  o.w = cw * inv * sc.w + bi.w;
  ((float4*)(out + (size_t)row * Hh))[t] = o;
}

// ---------------------------------------------------------------------------
extern "C" void kernel_launch(void* const* d_in, const int* in_sizes, int n_in,
                              void* d_out, int out_size, void* d_ws, size_t ws_size,
                              hipStream_t stream) {
  const float* enc      = (const float*)d_in[0];
  const float* rvals    = (const float*)d_in[1];
  const float* rscores  = (const float*)d_in[2];
  const float* Wm       = (const float*)d_in[3];
  const float* bias     = (const float*)d_in[4];
  const float* ln_scale = (const float*)d_in[5];
  const float* ln_bias  = (const float*)d_in[6];
  const int* bpos = (const int*)d_in[7];
  const int* spos = (const int*)d_in[8];
  // d_in[9] = mention_end_positions: unused by reference
  const int* mask = (const int*)d_in[10];
  float* out = (float*)d_out;

  char* ws = (char*)d_ws;
  float* weighted = (float*)ws;                                   // 8 MB
  float* proj = (float*)(ws + (size_t)Mm * Rr * 4);               // 8 MB
  int* head = (int*)(ws + (size_t)Mm * Rr * 4 + (size_t)Mm * Hh * 4); // 128 KB
  int* nxt = (int*)((char*)head + (size_t)Bb * Tt * 4);           // 8 KB

  hipLaunchKernelGGL(k_weighted, dim3(Mm), dim3(256), 0, stream,
                     rscores, rvals, weighted);
  hipLaunchKernelGGL(k_gemm, dim3(Hh / 64, Mm / 64), dim3(256), 0, stream,
                     weighted, Wm, bias, mask, proj);
  hipLaunchKernelGGL(k_init_head, dim3((Bb * Tt + 255) / 256), dim3(256), 0, stream,
                     head);
  hipLaunchKernelGGL(k_link, dim3((Mm + 255) / 256), dim3(256), 0, stream,
                     bpos, spos, mask, head, nxt);
  hipLaunchKernelGGL(k_ln, dim3(Bb * Tt), dim3(256), 0, stream,
                     enc, proj, head, nxt, ln_scale, ln_bias, out);
}